// Round 12
// baseline (325.425 us; speedup 1.0000x reference)
//
#include <hip/hip_runtime.h>
#include <math.h>

#define HW 65536
#define WD 256
#define HT 256

typedef short short8 __attribute__((ext_vector_type(8)));
typedef short sh4 __attribute__((ext_vector_type(4)));
typedef float f32x4 __attribute__((ext_vector_type(4)));
typedef __bf16 bf16x8 __attribute__((ext_vector_type(8)));
typedef __bf16 bf16x4 __attribute__((ext_vector_type(4)));

__device__ __forceinline__ short f2bf(float f) {
    union { float f; unsigned u; } v; v.f = f;
    unsigned r = (v.u + 0x7fffu + ((v.u >> 16) & 1u)) >> 16;
    return (short)r;
}

__device__ __forceinline__ float bf2f(short s) {
    union { unsigned u; float f; } v;
    v.u = ((unsigned)(unsigned short)s) << 16;
    return v.f;
}

__device__ __forceinline__ int iclamp(int v, int lo, int hi) {
    return v < lo ? lo : (v > hi ? hi : v);
}

struct Taps {
    int i00, i01, i10, i11;
    float w00, w01, w10, w11;
};

__device__ __forceinline__ Taps make_taps(float py, float px) {
    float fy0 = floorf(py), fx0 = floorf(px);
    float wy = py - fy0, wx = px - fx0;
    int y0 = (int)fy0, x0 = (int)fx0;
    int y1 = y0 + 1, x1 = x0 + 1;
    float vy0 = (y0 >= 0 && y0 <= HT - 1) ? 1.f : 0.f;
    float vy1 = (y1 >= 0 && y1 <= HT - 1) ? 1.f : 0.f;
    float vx0 = (x0 >= 0 && x0 <= WD - 1) ? 1.f : 0.f;
    float vx1 = (x1 >= 0 && x1 <= WD - 1) ? 1.f : 0.f;
    int yc0 = iclamp(y0, 0, HT - 1), yc1 = iclamp(y1, 0, HT - 1);
    int xc0 = iclamp(x0, 0, WD - 1), xc1 = iclamp(x1, 0, WD - 1);
    Taps t;
    t.i00 = yc0 * WD + xc0; t.i01 = yc0 * WD + xc1;
    t.i10 = yc1 * WD + xc0; t.i11 = yc1 * WD + xc1;
    t.w00 = (1.f - wy) * (1.f - wx) * vy0 * vx0;
    t.w01 = (1.f - wy) * wx * vy0 * vx1;
    t.w10 = wy * (1.f - wx) * vy1 * vx0;
    t.w11 = wy * wx * vy1 * vx1;
    return t;
}

// ---------------------------------------------------------------------------
// pack_nbr: nbr (B,64,HW) f32 -> N2 (B,8,HW,8) bf16 GROUP-MAJOR.
// Runs FIRST: N2 feeds pack_x1's warp gathers AND dcn's tap gathers.
// ---------------------------------------------------------------------------
__global__ __launch_bounds__(256) void pack_nbr_kernel(
    const float* __restrict__ nbr, short* __restrict__ N2)
{
    __shared__ short tile[64 * 66];
    int blk = blockIdx.x;              // b*1024 + grp
    int b = blk >> 10;
    int grp = blk & 1023;
    int px = threadIdx.x & 63;
    int qq = threadIdx.x >> 6;
    int pos = grp * 64 + px;

    const float* nb = nbr + (size_t)b * 64 * HW;
    #pragma unroll
    for (int j = 0; j < 16; ++j) {
        int c = qq * 16 + j;
        tile[px * 66 + c] = f2bf(nb[c * HW + pos]);
    }
    __syncthreads();

    short* xo = N2 + (size_t)b * HW * 64;
    #pragma unroll
    for (int f8 = threadIdx.x; f8 < 512; f8 += 256) {
        int g = f8 >> 6;        // group
        int p = f8 & 63;        // pixel (lanes contiguous -> coalesced)
        short8 v;
        #pragma unroll
        for (int j = 0; j < 8; ++j) v[j] = tile[p * 66 + g * 8 + j];
        *(short8*)(xo + ((size_t)g * HW + grp * 64 + p) * 8) = v;
    }
}

// ---------------------------------------------------------------------------
// pack_x1: warp from N2 (group-major bf16: 8 x 16B vector gathers/thread)
// + ref -> X1 (B,HW,128) NHWC bf16.
// ---------------------------------------------------------------------------
__global__ __launch_bounds__(256) void pack_x1_kernel(
    const short* __restrict__ N2, const float* __restrict__ ref,
    const float* __restrict__ flow, short* __restrict__ X1)
{
    __shared__ short tile[64 * 136];
    int blk = blockIdx.x;              // b*1024 + grp
    int b = blk >> 10;
    int grp = blk & 1023;
    int px = threadIdx.x & 63;
    int qq = threadIdx.x >> 6;
    int pos = grp * 64 + px;
    int yy = pos >> 8, xx = pos & 255;

    float fx = flow[b * 2 * HW + pos];
    float fy = flow[b * 2 * HW + HW + pos];
    Taps tp = make_taps((float)yy + fy, (float)xx + fx);

    const short* n2b = N2 + (size_t)b * HW * 64;
    const float* rf = ref + (size_t)b * 64 * HW;

    // warp channels: this thread covers groups qq*2, qq*2+1 (16 ch)
    #pragma unroll
    for (int gi = 0; gi < 2; ++gi) {
        int g = qq * 2 + gi;
        const short* nbg = n2b + (size_t)g * HW * 8;
        short8 a00 = *(const short8*)(nbg + (size_t)tp.i00 * 8);
        short8 a01 = *(const short8*)(nbg + (size_t)tp.i01 * 8);
        short8 a10 = *(const short8*)(nbg + (size_t)tp.i10 * 8);
        short8 a11 = *(const short8*)(nbg + (size_t)tp.i11 * 8);
        union { bf16x8 bv; short8 s; } u;
        #pragma unroll
        for (int c = 0; c < 8; ++c) {
            float s = tp.w00 * bf2f(a00[c]) + tp.w01 * bf2f(a01[c]) +
                      tp.w10 * bf2f(a10[c]) + tp.w11 * bf2f(a11[c]);
            u.bv[c] = (__bf16)s;
        }
        *(short8*)(&tile[px * 136 + g * 8]) = u.s;
    }
    // ref channels (coalesced channel-strided f32 reads)
    #pragma unroll
    for (int j = 0; j < 16; ++j) {
        int c = qq * 16 + j;
        tile[px * 136 + 64 + c] = f2bf(rf[c * HW + pos]);
    }
    __syncthreads();

    short* xo = X1 + ((size_t)b * HW + grp * 64) * 128;
    #pragma unroll
    for (int f8 = threadIdx.x; f8 < 1024; f8 += 256) {
        int p = (f8 * 8) >> 7;
        int c = (f8 * 8) & 127;
        short8 v;
        #pragma unroll
        for (int j = 0; j < 8; ++j) v[j] = tile[p * 136 + c + j];
        *(short8*)(xo + f8 * 8) = v;
    }
}

// ---------------------------------------------------------------------------
// Weight repacks to MFMA B-fragment order.
// ---------------------------------------------------------------------------
__global__ __launch_bounds__(256) void repack_w1_kernel(
    const float* __restrict__ w, short* __restrict__ wr)
{
    int t = blockIdx.x * 256 + threadIdx.x;  // 73728
    int j = t & 7, q = (t >> 3) & 3, l = (t >> 5) & 15;
    int nt = (t >> 9) & 3, kc = t >> 11;
    int k = kc * 32 + q * 8 + j;
    int rs = k >> 7, c = k & 127;
    int n = nt * 16 + l;
    wr[t] = f2bf(w[(n * 128 + c) * 9 + rs]);
}

// om weights -> B-frag order:
//   chunks 0..17: fea K (tap = k>>6, ch = k&63); chunk 18: flow (2*tap+u)
__global__ __launch_bounds__(256) void repack_w2_kernel(
    const float* __restrict__ w, short* __restrict__ wr)
{
    int t = blockIdx.x * 256 + threadIdx.x;  // 155648
    if (t >= 155648) return;
    int j = t & 7, q = (t >> 3) & 3, l = (t >> 5) & 15;
    int nt = (t >> 9) & 15, kc = t >> 13;
    int n = nt * 16 + l;
    float v = 0.f;
    if (kc < 18) {
        int k = kc * 32 + q * 8 + j;
        int rs = k >> 6, c = k & 63;
        if (n < 216) v = w[(n * 66 + c) * 9 + rs];
    } else {
        int k18 = q * 8 + j;
        if (k18 < 18 && n < 216) {
            int tap = k18 >> 1, u = k18 & 1;
            v = w[(n * 66 + 64 + u) * 9 + tap];
        }
    }
    wr[t] = f2bf(v);
}

// dcn weights -> B-frag order: flat = (((g*3+kc)*4+nt)*64 + l15*4+q)*8 + j
__global__ __launch_bounds__(256) void repack_dcn_kernel(
    const float* __restrict__ w, short* __restrict__ wr)
{
    int t = blockIdx.x * 256 + threadIdx.x;   // 49152
    int j = t & 7, q = (t >> 3) & 3, l = (t >> 5) & 15;
    int rem = t >> 9;           // (g*3+kc)*4 + nt
    int nt = rem & 3;
    int gkc = rem >> 2;         // g*3 + kc
    int kc = gkc % 3, g = gkc / 3;
    int Kidx = kc * 32 + q * 8 + j;
    int k = Kidx >> 3, c = Kidx & 7;
    int och = nt * 16 + l;
    float v = (k < 9) ? w[(och * 64 + g * 8 + c) * 9 + k] : 0.f;
    wr[t] = f2bf(v);
}

// ---------------------------------------------------------------------------
// conv1 MFMA: X1 (NHWC bf16, 128ch) -> X2 (NHWC bf16, 64ch fea only).
// ---------------------------------------------------------------------------
#define PADC1 128
__global__ __launch_bounds__(256) void conv1_mfma_kernel(
    const short* __restrict__ X1, const float* __restrict__ bias,
    const short* __restrict__ wr, short* __restrict__ X2)
{
    __shared__ short lds[198 * PADC1];
    const int tid = threadIdx.x;
    const int w = __builtin_amdgcn_readfirstlane(tid >> 6);
    const int l15 = tid & 15;
    const int q = (tid >> 4) & 3;
    const int blk = ((blockIdx.x & 7) << 8) | (blockIdx.x >> 3);  // XCD swizzle (2048 % 8 == 0)
    const int xseg = blk & 3;
    const int yy = (blk >> 2) & 255;
    const int b = blk >> 10;
    const int x0 = xseg * 64;

    const short* xin = X1 + (size_t)b * HW * 128;
    for (int i = tid; i < 198 * 16; i += 256) {
        int c16 = i & 15;
        int pix = i >> 4;
        int r = pix / 66, xx = pix % 66;
        int gy = yy + r - 1, gx = x0 + xx - 1;
        short8 v = {0, 0, 0, 0, 0, 0, 0, 0};
        if (gy >= 0 && gy < HT && gx >= 0 && gx < WD)
            v = *(const short8*)(xin + ((size_t)((gy << 8) + gx)) * 128 + c16 * 8);
        *(short8*)(&lds[pix * PADC1 + (c16 ^ (pix & 7)) * 8]) = v;
    }
    __syncthreads();

    f32x4 acc[4] = {{0,0,0,0},{0,0,0,0},{0,0,0,0},{0,0,0,0}};
    const int bbase = l15 * 4 + q;

    #define LOADB1(kc_) (*(const short8*)(wr + ((size_t)(((kc_) * 4 + w) * 64 + bbase)) * 8))
    #define COMP1(kc_, bf_) { \
        int rs_ = (kc_) >> 2, cc_ = (kc_) & 3; \
        int r_ = rs_ / 3, s_ = rs_ % 3; \
        int rowb_ = r_ * 66 + s_ + l15; \
        _Pragma("unroll") \
        for (int mt = 0; mt < 4; ++mt) { \
            int row_ = rowb_ + mt * 16; \
            int col16_ = (cc_ * 4 + q) ^ (row_ & 7); \
            short8 a_ = *(const short8*)(&lds[row_ * PADC1 + col16_ * 8]); \
            acc[mt] = __builtin_amdgcn_mfma_f32_16x16x32_bf16(a_, bf_, acc[mt], 0, 0, 0); \
        } }

    short8 bA = LOADB1(0), bB;
    #pragma unroll 1
    for (int jj = 0; jj < 18; ++jj) {
        int kc0 = 2 * jj;
        bB = LOADB1(kc0 + 1);
        COMP1(kc0, bA);
        int kc2 = kc0 + 2; if (kc2 > 35) kc2 = 35;
        bA = LOADB1(kc2);
        COMP1(kc0 + 1, bB);
    }
    #undef LOADB1
    #undef COMP1

    float bv = bias[w * 16 + l15];
    short* xo = X2 + (size_t)b * HW * 64;
    #pragma unroll
    for (int mt = 0; mt < 4; ++mt) {
        #pragma unroll
        for (int rg = 0; rg < 4; ++rg) {
            int px = x0 + mt * 16 + q * 4 + rg;
            float v = fmaxf(acc[mt][rg] + bv, 0.f);
            xo[((size_t)((yy << 8) + px)) * 64 + w * 16 + l15] = f2bf(v);
        }
    }
}

// ---------------------------------------------------------------------------
// om MFMA: X2 (NHWC bf16, 64ch) + flow halo -> OFF (B,144,HW) f32 offsets
// + MB (B,72,HW) bf16 mask (sigmoid applied HERE, stored post-activation).
// M=128 px / block (grid 1024), acc[4][8].
// ---------------------------------------------------------------------------
#define PADX2 64
__global__ __launch_bounds__(256, 2) void om_mfma_kernel(
    const short* __restrict__ X2, const float* __restrict__ flow,
    const short* __restrict__ wr, const float* __restrict__ bias,
    float* __restrict__ OFF, short* __restrict__ MB)
{
    __shared__ __align__(16) char ldsraw[67584];
    short* ldsA = (short*)ldsraw;                  // [390][64] swizzled fea halo
    short* A18  = (short*)(ldsraw + 49920);        // [128][34] flow K-chunk
    float* ldsT = (float*)ldsraw;                  // [128][132] epilogue alias

    const int tid = threadIdx.x;
    const int w = __builtin_amdgcn_readfirstlane(tid >> 6);
    const int l15 = tid & 15;
    const int q = (tid >> 4) & 3;
    const int blk = ((blockIdx.x & 7) << 7) | (blockIdx.x >> 3);  // XCD swizzle (1024)
    const int xseg = blk & 1;
    const int yy = (blk >> 1) & 255;
    const int b = blk >> 9;
    const int x0 = xseg * 128;

    // stage fea halo: 3 rows x 130 px x 64 ch, XOR-swizzled 16B blocks
    const short* xin = X2 + (size_t)b * HW * 64;
    #pragma unroll
    for (int r = 0; r < 3; ++r) {
        int gy = yy + r - 1;
        for (int i = tid; i < 130 * 8; i += 256) {
            int xx = i >> 3, c8 = i & 7;
            int gx = x0 + xx - 1;
            short8 v = {0, 0, 0, 0, 0, 0, 0, 0};
            if (gy >= 0 && gy < HT && gx >= 0 && gx < WD)
                v = *(const short8*)(xin + ((size_t)((gy << 8) + gx)) * 64 + c8 * 8);
            int pix = r * 130 + xx;
            *(short8*)(&ldsA[pix * PADX2 + (c8 ^ (pix & 7)) * 8]) = v;
        }
    }
    // stage flow A-chunk [128 px][34]: cols 0..17 = flow halo, 18..31 zero
    for (int i = tid; i < 128 * 32; i += 256) {
        int p = i >> 5, kk = i & 31;
        short v = 0;
        if (kk < 18) {
            int tap = kk >> 1, u = kk & 1;
            int gy = yy + tap / 3 - 1, gx = x0 + p + tap % 3 - 1;
            if (gy >= 0 && gy < HT && gx >= 0 && gx < WD)
                v = f2bf(flow[(size_t)(b * 2 + u) * HW + (gy << 8) + gx]);
        }
        A18[p * 34 + kk] = v;
    }
    __syncthreads();

    f32x4 acc[4][8];
    #pragma unroll
    for (int i = 0; i < 4; ++i)
        #pragma unroll
        for (int mt = 0; mt < 8; ++mt) acc[i][mt] = (f32x4){0, 0, 0, 0};

    const int bbase = l15 * 4 + q;

    #define LOADB2(dst_, kc_) { \
        _Pragma("unroll") \
        for (int i = 0; i < 4; ++i) \
            dst_[i] = *(const short8*)(wr + ((size_t)(((kc_) * 16 + w * 4 + i) * 64 + bbase)) * 8); }
    #define COMP2(kc_, bf_) { \
        int rs_ = (kc_) >> 1, half_ = (kc_) & 1; \
        int r_ = rs_ / 3, s_ = rs_ % 3; \
        int rowb_ = r_ * 130 + s_ + l15; \
        _Pragma("unroll") \
        for (int mt = 0; mt < 8; ++mt) { \
            int row_ = rowb_ + mt * 16; \
            int col16_ = (half_ * 4 + q) ^ (row_ & 7); \
            short8 a_ = *(const short8*)(&ldsA[row_ * PADX2 + col16_ * 8]); \
            _Pragma("unroll") \
            for (int i = 0; i < 4; ++i) \
                acc[i][mt] = __builtin_amdgcn_mfma_f32_16x16x32_bf16(a_, bf_[i], acc[i][mt], 0, 0, 0); \
        } }

    short8 bA[4], bB[4];
    LOADB2(bA, 0);
    #pragma unroll 1
    for (int jj = 0; jj < 9; ++jj) {
        int kc0 = 2 * jj;
        LOADB2(bB, kc0 + 1);
        COMP2(kc0, bA);
        LOADB2(bA, kc0 + 2);     // jj==8 -> loads chunk 18 (flow B-frags)
        COMP2(kc0 + 1, bB);
    }
    // flow chunk (kc 18): A from A18
    #pragma unroll
    for (int mt = 0; mt < 8; ++mt) {
        short8 a_ = *(const short8*)(&A18[(mt * 16 + l15) * 34 + q * 8]);
        #pragma unroll
        for (int i = 0; i < 4; ++i)
            acc[i][mt] = __builtin_amdgcn_mfma_f32_16x16x32_bf16(a_, bA[i], acc[i][mt], 0, 0, 0);
    }
    #undef LOADB2
    #undef COMP2

    // epilogue: 2 passes; ch<144 -> OFF f32x4; ch>=144 -> sigmoid -> MB bf16
    #pragma unroll 1
    for (int pass = 0; pass < 2; ++pass) {
        __syncthreads();
        if ((w >> 1) == pass) {
            int ochl_base = (w & 1) * 64;
            #pragma unroll
            for (int i = 0; i < 4; ++i) {
                int ochl = ochl_base + i * 16 + l15;
                #pragma unroll
                for (int mt = 0; mt < 8; ++mt)
                    #pragma unroll
                    for (int rg = 0; rg < 4; ++rg)
                        ldsT[ochl * 132 + mt * 16 + q * 4 + rg] = acc[i][mt][rg];
            }
        }
        __syncthreads();
        for (int f = tid; f < 128 * 32; f += 256) {
            int chl = f >> 5, p16 = (f & 31) * 4;
            int ch = pass * 128 + chl;
            if (ch < 216) {
                f32x4 v = *(const f32x4*)(&ldsT[chl * 132 + p16]);
                float bv = bias[ch];
                if (ch < 144) {
                    v[0] += bv; v[1] += bv; v[2] += bv; v[3] += bv;
                    *(f32x4*)(&OFF[((size_t)b * 144 + ch) * HW + (yy << 8) + x0 + p16]) = v;
                } else {
                    union { bf16x4 bv4; sh4 s4; } u;
                    #pragma unroll
                    for (int j = 0; j < 4; ++j) {
                        float m = 1.f / (1.f + __expf(-(v[j] + bv)));
                        u.bv4[j] = (__bf16)m;
                    }
                    *(sh4*)(&MB[((size_t)b * 72 + (ch - 144)) * HW + (yy << 8) + x0 + p16]) = u.s4;
                }
            }
        }
    }
}

// ---------------------------------------------------------------------------
// dcn MFMA — pipelined; offsets from OFF (f32), mask from MB (bf16).
// Plain __launch_bounds__(256): round-10's ",4" capped VGPR at 64 and
// serialized the 12-gather window (VALUBusy 50->39, +5us).
// Epilogue: ldsT stride 68 (16B-aligned rows) + f32x4 writes/stores.
// ---------------------------------------------------------------------------
__global__ __launch_bounds__(256) void dcn_mfma_kernel(
    const float* __restrict__ OFF,    // (B,144,HW) f32
    const short* __restrict__ MB,     // (B,72,HW) bf16 sigmoid(mask)
    const float* __restrict__ flow,   // (B,2,HW)
    const short* __restrict__ N2,     // (B,8,HW,8) bf16 group-major
    const short* __restrict__ wrd,    // B-frag order, 49152
    const float* __restrict__ bias,   // 64
    float* __restrict__ out)          // (B,64,HW)
{
    __shared__ __align__(16) char ldsraw[26624];
    short* bufA = (short*)ldsraw;                 // [64 px][104]
    short* bufB = (short*)(ldsraw + 13312);       // [64 px][104]
    float* ldsT = (float*)ldsraw;                 // [64 och][68] epilogue alias

    const int tid = threadIdx.x;
    const int w = __builtin_amdgcn_readfirstlane(tid >> 6);
    const int l15 = tid & 15;
    const int q = (tid >> 4) & 3;
    const int qq = tid >> 6;
    const int px = tid & 63;

    const int blk = ((blockIdx.x & 7) << 8) | (blockIdx.x >> 3);  // XCD swizzle
    const int b = blk >> 10;
    const int grp = blk & 1023;
    const int pos0 = grp * 64;
    const int pos = pos0 + px;
    const int yy = pos >> 8, xx = pos & 255;

    const float* offb = OFF + (size_t)b * 144 * HW + pos;
    const short* mbp  = MB + (size_t)b * 72 * HW + pos;
    const float fx = flow[b * 2 * HW + pos];
    const float fy = flow[b * 2 * HW + HW + pos];
    const short* n2b = N2 + (size_t)b * HW * 64;

    // zero pad K-slots (k = 9..11) in BOTH buffers once
    {
        short8 z = {0, 0, 0, 0, 0, 0, 0, 0};
        #pragma unroll
        for (int it = 0; it < 3; ++it) {
            int k = qq + 4 * it;
            if (k >= 9) {
                *(short8*)(&bufA[px * 104 + k * 8]) = z;
                *(short8*)(&bufB[px * 104 + k * 8]) = z;
            }
        }
    }

    f32x4 acc[4] = {{0,0,0,0},{0,0,0,0},{0,0,0,0},{0,0,0,0}};

    // raw offset/mask loads for g=0
    float rdy[3], rdx[3];
    short rms[3];
    #pragma unroll
    for (int it = 0; it < 3; ++it) {
        int k = qq + 4 * it;
        rdy[it] = 0.f; rdx[it] = 0.f; rms[it] = 0;
        if (k < 9) {
            rdy[it] = offb[(size_t)(2 * k) * HW];
            rdx[it] = offb[(size_t)(2 * k + 1) * HW];
            rms[it] = mbp[(size_t)k * HW];
        }
    }

    // ---- prologue: fill group 0 into bufA ----
    {
        const short* nbg = n2b;                    // group 0 plane
        float w00[3], w01[3], w10[3], w11[3];
        short8 a00[3], a01[3], a10[3], a11[3];
        #pragma unroll
        for (int it = 0; it < 3; ++it) {
            int k = qq + 4 * it;
            if (k < 9) {
                float dy = rdy[it] + fy, dx = rdx[it] + fx;
                float m = bf2f(rms[it]);
                Taps tp = make_taps((float)(yy - 1 + k / 3) + dy,
                                    (float)(xx - 1 + k % 3) + dx);
                w00[it] = tp.w00 * m; w01[it] = tp.w01 * m;
                w10[it] = tp.w10 * m; w11[it] = tp.w11 * m;
                a00[it] = *(const short8*)(nbg + (size_t)tp.i00 * 8);
                a01[it] = *(const short8*)(nbg + (size_t)tp.i01 * 8);
                a10[it] = *(const short8*)(nbg + (size_t)tp.i10 * 8);
                a11[it] = *(const short8*)(nbg + (size_t)tp.i11 * 8);
            }
        }
        // prefetch raw g=1 (after the gathers: stays in flight through blend)
        #pragma unroll
        for (int it = 0; it < 3; ++it) {
            int k = qq + 4 * it;
            if (k < 9) {
                rdy[it] = offb[(size_t)(18 + 2 * k) * HW];
                rdx[it] = offb[(size_t)(18 + 2 * k + 1) * HW];
                rms[it] = mbp[(size_t)(9 + k) * HW];
            }
        }
        #pragma unroll
        for (int it = 0; it < 3; ++it) {
            int k = qq + 4 * it;
            if (k < 9) {
                union { bf16x8 bv; short8 s; } u;
                #pragma unroll
                for (int c = 0; c < 8; ++c) {
                    float s = w00[it] * bf2f(a00[it][c]) + w01[it] * bf2f(a01[it][c]) +
                              w10[it] * bf2f(a10[it][c]) + w11[it] * bf2f(a11[it][c]);
                    u.bv[c] = (__bf16)s;
                }
                *(short8*)(&bufA[px * 104 + k * 8]) = u.s;
            }
        }
    }
    __syncthreads();

    // ---- pipelined main loop: one barrier per group ----
    #pragma unroll 1
    for (int g = 0; g < 8; ++g) {
        short* cur = (g & 1) ? bufB : bufA;
        short* nxt = (g & 1) ? bufA : bufB;

        // issue gathers for group g+1 (12 loads in flight across the MFMAs)
        float w00[3], w01[3], w10[3], w11[3];
        short8 a00[3], a01[3], a10[3], a11[3];
        if (g < 7) {
            const short* nbg = n2b + (size_t)(g + 1) * HW * 8;
            #pragma unroll
            for (int it = 0; it < 3; ++it) {
                int k = qq + 4 * it;
                if (k < 9) {
                    float dy = rdy[it] + fy, dx = rdx[it] + fx;
                    float m = bf2f(rms[it]);
                    Taps tp = make_taps((float)(yy - 1 + k / 3) + dy,
                                        (float)(xx - 1 + k % 3) + dx);
                    w00[it] = tp.w00 * m; w01[it] = tp.w01 * m;
                    w10[it] = tp.w10 * m; w11[it] = tp.w11 * m;
                    a00[it] = *(const short8*)(nbg + (size_t)tp.i00 * 8);
                    a01[it] = *(const short8*)(nbg + (size_t)tp.i01 * 8);
                    a10[it] = *(const short8*)(nbg + (size_t)tp.i10 * 8);
                    a11[it] = *(const short8*)(nbg + (size_t)tp.i11 * 8);
                }
            }
            // prefetch raw for g+2 (after gathers: not drained by their wait)
            if (g < 6) {
                #pragma unroll
                for (int it = 0; it < 3; ++it) {
                    int k = qq + 4 * it;
                    if (k < 9) {
                        rdy[it] = offb[(size_t)((g + 2) * 18 + 2 * k) * HW];
                        rdx[it] = offb[(size_t)((g + 2) * 18 + 2 * k + 1) * HW];
                        rms[it] = mbp[(size_t)((g + 2) * 9 + k) * HW];
                    }
                }
            }
        }

        // MFMA group g from cur (hides the gather latency)
        #pragma unroll
        for (int kc = 0; kc < 3; ++kc) {
            short8 bfrag = *(const short8*)(wrd +
                ((size_t)(((g * 3 + kc) * 4 + w) * 64 + l15 * 4 + q)) * 8);
            #pragma unroll
            for (int mt = 0; mt < 4; ++mt) {
                short8 a = *(const short8*)(&cur[(mt * 16 + l15) * 104 + kc * 32 + q * 8]);
                acc[mt] = __builtin_amdgcn_mfma_f32_16x16x32_bf16(a, bfrag, acc[mt], 0, 0, 0);
            }
        }

        // blend g+1 -> nxt
        if (g < 7) {
            #pragma unroll
            for (int it = 0; it < 3; ++it) {
                int k = qq + 4 * it;
                if (k < 9) {
                    union { bf16x8 bv; short8 s; } u;
                    #pragma unroll
                    for (int c = 0; c < 8; ++c) {
                        float s = w00[it] * bf2f(a00[it][c]) + w01[it] * bf2f(a01[it][c]) +
                                  w10[it] * bf2f(a10[it][c]) + w11[it] * bf2f(a11[it][c]);
                        u.bv[c] = (__bf16)s;
                    }
                    *(short8*)(&nxt[px * 104 + k * 8]) = u.s;
                }
            }
        }
        __syncthreads();
    }

    // epilogue: LDS transpose (stride 68 -> 16B-aligned f32x4 rows) ->
    // vectorized NCHW stores (+bias)
    #pragma unroll
    for (int mt = 0; mt < 4; ++mt)
        *(f32x4*)(&ldsT[(w * 16 + l15) * 68 + mt * 16 + q * 4]) = acc[mt];
    __syncthreads();
    float* ob = out + (size_t)b * 64 * HW + pos0;
    #pragma unroll
    for (int f = tid; f < 1024; f += 256) {
        int och = f >> 4, p4 = (f & 15) * 4;
        f32x4 v = *(const f32x4*)(&ldsT[och * 68 + p4]);
        float bv = bias[och];
        v[0] += bv; v[1] += bv; v[2] += bv; v[3] += bv;
        *(f32x4*)(&ob[(size_t)och * HW + p4]) = v;
    }
}

// ---------------------------------------------------------------------------
extern "C" void kernel_launch(void* const* d_in, const int* in_sizes, int n_in,
                              void* d_out, int out_size, void* d_ws, size_t ws_size,
                              hipStream_t stream)
{
    const float* nbr  = (const float*)d_in[0];
    const float* ref  = (const float*)d_in[1];
    const float* flow = (const float*)d_in[2];
    const float* c1w  = (const float*)d_in[3];
    const float* c1b  = (const float*)d_in[4];
    const float* omw  = (const float*)d_in[5];
    const float* omb  = (const float*)d_in[6];
    const float* dw   = (const float*)d_in[7];
    const float* db   = (const float*)d_in[8];
    float* out = (float*)d_out;

    char* wsb = (char*)d_ws;
    short* X1    = (short*)(wsb);                  // 33,554,432 B
    short* X2    = (short*)(wsb + 33554432);       // 16,777,216 B
    short* N2    = (short*)(wsb + 50331648);       // 16,777,216 B
    float* OFF   = (float*)(wsb + 67108864);       // 75,497,472 B (B,144,HW f32)
    short* MB    = (short*)(wsb + 142606336);      // 18,874,368 B (B,72,HW bf16)
    short* wr1   = (short*)(wsb + 161480704);      // 147,456 B
    short* wr2   = (short*)(wsb + 161628160);      // 311,296 B
    short* wrd   = (short*)(wsb + 161939456);      // 98,304 B -> total 162,037,760 B

    repack_w1_kernel<<<288, 256, 0, stream>>>(c1w, wr1);
    repack_w2_kernel<<<608, 256, 0, stream>>>(omw, wr2);
    repack_dcn_kernel<<<192, 256, 0, stream>>>(dw, wrd);
    pack_nbr_kernel<<<2048, 256, 0, stream>>>(nbr, N2);
    pack_x1_kernel<<<2048, 256, 0, stream>>>(N2, ref, flow, X1);
    conv1_mfma_kernel<<<2048, 256, 0, stream>>>(X1, c1b, wr1, X2);
    om_mfma_kernel<<<1024, 256, 0, stream>>>(X2, flow, wr2, omb, OFF, MB);
    dcn_mfma_kernel<<<2048, 256, 0, stream>>>(OFF, MB, flow, N2, wrd, db, out);
}

// Round 13
// 322.114 us; speedup vs baseline: 1.0103x; 1.0103x over previous
//
#include <hip/hip_runtime.h>
#include <math.h>

#define HW 65536
#define WD 256
#define HT 256

typedef short short8 __attribute__((ext_vector_type(8)));
typedef short sh4 __attribute__((ext_vector_type(4)));
typedef float f32x4 __attribute__((ext_vector_type(4)));
typedef __bf16 bf16x8 __attribute__((ext_vector_type(8)));
typedef __bf16 bf16x4 __attribute__((ext_vector_type(4)));

__device__ __forceinline__ short f2bf(float f) {
    union { float f; unsigned u; } v; v.f = f;
    unsigned r = (v.u + 0x7fffu + ((v.u >> 16) & 1u)) >> 16;
    return (short)r;
}

__device__ __forceinline__ float bf2f(short s) {
    union { unsigned u; float f; } v;
    v.u = ((unsigned)(unsigned short)s) << 16;
    return v.f;
}

__device__ __forceinline__ int iclamp(int v, int lo, int hi) {
    return v < lo ? lo : (v > hi ? hi : v);
}

struct Taps {
    int i00, i01, i10, i11;
    float w00, w01, w10, w11;
};

__device__ __forceinline__ Taps make_taps(float py, float px) {
    float fy0 = floorf(py), fx0 = floorf(px);
    float wy = py - fy0, wx = px - fx0;
    int y0 = (int)fy0, x0 = (int)fx0;
    int y1 = y0 + 1, x1 = x0 + 1;
    float vy0 = (y0 >= 0 && y0 <= HT - 1) ? 1.f : 0.f;
    float vy1 = (y1 >= 0 && y1 <= HT - 1) ? 1.f : 0.f;
    float vx0 = (x0 >= 0 && x0 <= WD - 1) ? 1.f : 0.f;
    float vx1 = (x1 >= 0 && x1 <= WD - 1) ? 1.f : 0.f;
    int yc0 = iclamp(y0, 0, HT - 1), yc1 = iclamp(y1, 0, HT - 1);
    int xc0 = iclamp(x0, 0, WD - 1), xc1 = iclamp(x1, 0, WD - 1);
    Taps t;
    t.i00 = yc0 * WD + xc0; t.i01 = yc0 * WD + xc1;
    t.i10 = yc1 * WD + xc0; t.i11 = yc1 * WD + xc1;
    t.w00 = (1.f - wy) * (1.f - wx) * vy0 * vx0;
    t.w01 = (1.f - wy) * wx * vy0 * vx1;
    t.w10 = wy * (1.f - wx) * vy1 * vx0;
    t.w11 = wy * wx * vy1 * vx1;
    return t;
}

// ---------------------------------------------------------------------------
// pack_nbr: nbr (B,64,HW) f32 -> N2 (B,8,HW,8) bf16 GROUP-MAJOR.
// Runs FIRST: N2 feeds pack_x1's warp gathers AND dcn's tap gathers.
// ---------------------------------------------------------------------------
__global__ __launch_bounds__(256) void pack_nbr_kernel(
    const float* __restrict__ nbr, short* __restrict__ N2)
{
    __shared__ short tile[64 * 66];
    int blk = blockIdx.x;              // b*1024 + grp
    int b = blk >> 10;
    int grp = blk & 1023;
    int px = threadIdx.x & 63;
    int qq = threadIdx.x >> 6;
    int pos = grp * 64 + px;

    const float* nb = nbr + (size_t)b * 64 * HW;
    #pragma unroll
    for (int j = 0; j < 16; ++j) {
        int c = qq * 16 + j;
        tile[px * 66 + c] = f2bf(nb[c * HW + pos]);
    }
    __syncthreads();

    short* xo = N2 + (size_t)b * HW * 64;
    #pragma unroll
    for (int f8 = threadIdx.x; f8 < 512; f8 += 256) {
        int g = f8 >> 6;        // group
        int p = f8 & 63;        // pixel (lanes contiguous -> coalesced)
        short8 v;
        #pragma unroll
        for (int j = 0; j < 8; ++j) v[j] = tile[p * 66 + g * 8 + j];
        *(short8*)(xo + ((size_t)g * HW + grp * 64 + p) * 8) = v;
    }
}

// ---------------------------------------------------------------------------
// pack_x1: warp from N2 (group-major bf16: 8 x 16B vector gathers/thread)
// + ref -> X1 (B,HW,128) NHWC bf16.
// ---------------------------------------------------------------------------
__global__ __launch_bounds__(256) void pack_x1_kernel(
    const short* __restrict__ N2, const float* __restrict__ ref,
    const float* __restrict__ flow, short* __restrict__ X1)
{
    __shared__ short tile[64 * 136];
    int blk = blockIdx.x;              // b*1024 + grp
    int b = blk >> 10;
    int grp = blk & 1023;
    int px = threadIdx.x & 63;
    int qq = threadIdx.x >> 6;
    int pos = grp * 64 + px;
    int yy = pos >> 8, xx = pos & 255;

    float fx = flow[b * 2 * HW + pos];
    float fy = flow[b * 2 * HW + HW + pos];
    Taps tp = make_taps((float)yy + fy, (float)xx + fx);

    const short* n2b = N2 + (size_t)b * HW * 64;
    const float* rf = ref + (size_t)b * 64 * HW;

    // warp channels: this thread covers groups qq*2, qq*2+1 (16 ch)
    #pragma unroll
    for (int gi = 0; gi < 2; ++gi) {
        int g = qq * 2 + gi;
        const short* nbg = n2b + (size_t)g * HW * 8;
        short8 a00 = *(const short8*)(nbg + (size_t)tp.i00 * 8);
        short8 a01 = *(const short8*)(nbg + (size_t)tp.i01 * 8);
        short8 a10 = *(const short8*)(nbg + (size_t)tp.i10 * 8);
        short8 a11 = *(const short8*)(nbg + (size_t)tp.i11 * 8);
        union { bf16x8 bv; short8 s; } u;
        #pragma unroll
        for (int c = 0; c < 8; ++c) {
            float s = tp.w00 * bf2f(a00[c]) + tp.w01 * bf2f(a01[c]) +
                      tp.w10 * bf2f(a10[c]) + tp.w11 * bf2f(a11[c]);
            u.bv[c] = (__bf16)s;
        }
        *(short8*)(&tile[px * 136 + g * 8]) = u.s;
    }
    // ref channels (coalesced channel-strided f32 reads)
    #pragma unroll
    for (int j = 0; j < 16; ++j) {
        int c = qq * 16 + j;
        tile[px * 136 + 64 + c] = f2bf(rf[c * HW + pos]);
    }
    __syncthreads();

    short* xo = X1 + ((size_t)b * HW + grp * 64) * 128;
    #pragma unroll
    for (int f8 = threadIdx.x; f8 < 1024; f8 += 256) {
        int p = (f8 * 8) >> 7;
        int c = (f8 * 8) & 127;
        short8 v;
        #pragma unroll
        for (int j = 0; j < 8; ++j) v[j] = tile[p * 136 + c + j];
        *(short8*)(xo + f8 * 8) = v;
    }
}

// ---------------------------------------------------------------------------
// Weight repacks to MFMA B-fragment order.
// ---------------------------------------------------------------------------
__global__ __launch_bounds__(256) void repack_w1_kernel(
    const float* __restrict__ w, short* __restrict__ wr)
{
    int t = blockIdx.x * 256 + threadIdx.x;  // 73728
    int j = t & 7, q = (t >> 3) & 3, l = (t >> 5) & 15;
    int nt = (t >> 9) & 3, kc = t >> 11;
    int k = kc * 32 + q * 8 + j;
    int rs = k >> 7, c = k & 127;
    int n = nt * 16 + l;
    wr[t] = f2bf(w[(n * 128 + c) * 9 + rs]);
}

// om weights -> B-frag order:
//   chunks 0..17: fea K (tap = k>>6, ch = k&63); chunk 18: flow (2*tap+u)
__global__ __launch_bounds__(256) void repack_w2_kernel(
    const float* __restrict__ w, short* __restrict__ wr)
{
    int t = blockIdx.x * 256 + threadIdx.x;  // 155648
    if (t >= 155648) return;
    int j = t & 7, q = (t >> 3) & 3, l = (t >> 5) & 15;
    int nt = (t >> 9) & 15, kc = t >> 13;
    int n = nt * 16 + l;
    float v = 0.f;
    if (kc < 18) {
        int k = kc * 32 + q * 8 + j;
        int rs = k >> 6, c = k & 63;
        if (n < 216) v = w[(n * 66 + c) * 9 + rs];
    } else {
        int k18 = q * 8 + j;
        if (k18 < 18 && n < 216) {
            int tap = k18 >> 1, u = k18 & 1;
            v = w[(n * 66 + 64 + u) * 9 + tap];
        }
    }
    wr[t] = f2bf(v);
}

// dcn weights -> B-frag order: flat = (((g*3+kc)*4+nt)*64 + l15*4+q)*8 + j
__global__ __launch_bounds__(256) void repack_dcn_kernel(
    const float* __restrict__ w, short* __restrict__ wr)
{
    int t = blockIdx.x * 256 + threadIdx.x;   // 49152
    int j = t & 7, q = (t >> 3) & 3, l = (t >> 5) & 15;
    int rem = t >> 9;           // (g*3+kc)*4 + nt
    int nt = rem & 3;
    int gkc = rem >> 2;         // g*3 + kc
    int kc = gkc % 3, g = gkc / 3;
    int Kidx = kc * 32 + q * 8 + j;
    int k = Kidx >> 3, c = Kidx & 7;
    int och = nt * 16 + l;
    float v = (k < 9) ? w[(och * 64 + g * 8 + c) * 9 + k] : 0.f;
    wr[t] = f2bf(v);
}

// ---------------------------------------------------------------------------
// conv1 MFMA: X1 (NHWC bf16, 128ch) -> X2 (NHWC bf16, 64ch fea only).
// 4-ROW BLOCKS (grid 512): halo staging redundancy 3.1x -> 1.55x (stage
// loads per output px halved). K processed in two 64-ch halves reusing one
// 49.5 KB LDS buffer (chunks kc%4 in {0,1} then {2,3}; both accumulate the
// same acc). Wave w owns output row w x all 64 och (acc[4][4]).
// ---------------------------------------------------------------------------
__global__ __launch_bounds__(256) void conv1_mfma_kernel(
    const short* __restrict__ X1, const float* __restrict__ bias,
    const short* __restrict__ wr, short* __restrict__ X2)
{
    __shared__ short lds[396 * 64];
    const int tid = threadIdx.x;
    const int w = __builtin_amdgcn_readfirstlane(tid >> 6);
    const int l15 = tid & 15;
    const int q = (tid >> 4) & 3;
    const int blk = ((blockIdx.x & 7) << 6) | (blockIdx.x >> 3);  // XCD swizzle (512 % 8 == 0)
    const int xseg = blk & 3;
    const int yq = (blk >> 2) & 63;
    const int b = blk >> 8;
    const int x0 = xseg * 64;
    const int y0r = yq * 4;

    const short* xin = X1 + (size_t)b * HW * 128;
    const int bbase = l15 * 4 + q;

    f32x4 acc[4][4];
    #pragma unroll
    for (int ot = 0; ot < 4; ++ot)
        #pragma unroll
        for (int mt = 0; mt < 4; ++mt) acc[ot][mt] = (f32x4){0, 0, 0, 0};

    #define LOADB1(dst_, t_) { \
        int kc_ = ((t_) >> 1) * 4 + h * 2 + ((t_) & 1); \
        _Pragma("unroll") \
        for (int ot = 0; ot < 4; ++ot) \
            dst_[ot] = *(const short8*)(wr + ((size_t)((kc_ * 4 + ot) * 64 + bbase)) * 8); }
    #define COMP1(t_, bf_) { \
        int rs_ = (t_) >> 1, cch_ = (t_) & 1; \
        int r_ = rs_ / 3, s_ = rs_ % 3; \
        int prow_ = (w + r_) * 66 + s_ + l15; \
        _Pragma("unroll") \
        for (int mt = 0; mt < 4; ++mt) { \
            int pr_ = prow_ + mt * 16; \
            int col16_ = (cch_ * 4 + q) ^ (pr_ & 7); \
            short8 a_ = *(const short8*)(&lds[pr_ * 64 + col16_ * 8]); \
            _Pragma("unroll") \
            for (int ot = 0; ot < 4; ++ot) \
                acc[ot][mt] = __builtin_amdgcn_mfma_f32_16x16x32_bf16(a_, bf_[ot], acc[ot][mt], 0, 0, 0); \
        } }

    #pragma unroll 1
    for (int h = 0; h < 2; ++h) {
        __syncthreads();       // protect lds from previous half's reads
        for (int i = tid; i < 396 * 8; i += 256) {
            int c8 = i & 7;
            int pix = i >> 3;
            int r = pix / 66, xx = pix - r * 66;
            int gy = y0r + r - 1, gx = x0 + xx - 1;
            short8 v = {0, 0, 0, 0, 0, 0, 0, 0};
            if (gy >= 0 && gy < HT && gx >= 0 && gx < WD)
                v = *(const short8*)(xin + ((size_t)((gy << 8) + gx)) * 128 + h * 64 + c8 * 8);
            *(short8*)(&lds[pix * 64 + ((c8 ^ (pix & 7)) * 8)]) = v;
        }
        __syncthreads();

        short8 bA[4], bB[4];
        LOADB1(bA, 0);
        #pragma unroll 1
        for (int jj = 0; jj < 9; ++jj) {
            int t0 = 2 * jj;
            LOADB1(bB, t0 + 1);
            COMP1(t0, bA);
            int t2 = t0 + 2; if (t2 > 17) t2 = 17;
            LOADB1(bA, t2);
            COMP1(t0 + 1, bB);
        }
    }
    #undef LOADB1
    #undef COMP1

    short* xo = X2 + (size_t)b * HW * 64;
    const int gyy = y0r + w;
    #pragma unroll
    for (int ot = 0; ot < 4; ++ot) {
        float bv = bias[ot * 16 + l15];
        #pragma unroll
        for (int mt = 0; mt < 4; ++mt) {
            #pragma unroll
            for (int rg = 0; rg < 4; ++rg) {
                int gpx = x0 + mt * 16 + q * 4 + rg;
                float v = fmaxf(acc[ot][mt][rg] + bv, 0.f);
                xo[((size_t)((gyy << 8) + gpx)) * 64 + ot * 16 + l15] = f2bf(v);
            }
        }
    }
}

// ---------------------------------------------------------------------------
// om MFMA: X2 (NHWC bf16, 64ch) + flow halo -> OFF (B,144,HW) f32 offsets
// + MB (B,72,HW) bf16 mask (sigmoid applied HERE, stored post-activation).
// M=128 px / block (grid 1024), acc[4][8].
// ---------------------------------------------------------------------------
#define PADX2 64
__global__ __launch_bounds__(256, 2) void om_mfma_kernel(
    const short* __restrict__ X2, const float* __restrict__ flow,
    const short* __restrict__ wr, const float* __restrict__ bias,
    float* __restrict__ OFF, short* __restrict__ MB)
{
    __shared__ __align__(16) char ldsraw[67584];
    short* ldsA = (short*)ldsraw;                  // [390][64] swizzled fea halo
    short* A18  = (short*)(ldsraw + 49920);        // [128][34] flow K-chunk
    float* ldsT = (float*)ldsraw;                  // [128][132] epilogue alias

    const int tid = threadIdx.x;
    const int w = __builtin_amdgcn_readfirstlane(tid >> 6);
    const int l15 = tid & 15;
    const int q = (tid >> 4) & 3;
    const int blk = ((blockIdx.x & 7) << 7) | (blockIdx.x >> 3);  // XCD swizzle (1024)
    const int xseg = blk & 1;
    const int yy = (blk >> 1) & 255;
    const int b = blk >> 9;
    const int x0 = xseg * 128;

    // stage fea halo: 3 rows x 130 px x 64 ch, XOR-swizzled 16B blocks
    const short* xin = X2 + (size_t)b * HW * 64;
    #pragma unroll
    for (int r = 0; r < 3; ++r) {
        int gy = yy + r - 1;
        for (int i = tid; i < 130 * 8; i += 256) {
            int xx = i >> 3, c8 = i & 7;
            int gx = x0 + xx - 1;
            short8 v = {0, 0, 0, 0, 0, 0, 0, 0};
            if (gy >= 0 && gy < HT && gx >= 0 && gx < WD)
                v = *(const short8*)(xin + ((size_t)((gy << 8) + gx)) * 64 + c8 * 8);
            int pix = r * 130 + xx;
            *(short8*)(&ldsA[pix * PADX2 + (c8 ^ (pix & 7)) * 8]) = v;
        }
    }
    // stage flow A-chunk [128 px][34]: cols 0..17 = flow halo, 18..31 zero
    for (int i = tid; i < 128 * 32; i += 256) {
        int p = i >> 5, kk = i & 31;
        short v = 0;
        if (kk < 18) {
            int tap = kk >> 1, u = kk & 1;
            int gy = yy + tap / 3 - 1, gx = x0 + p + tap % 3 - 1;
            if (gy >= 0 && gy < HT && gx >= 0 && gx < WD)
                v = f2bf(flow[(size_t)(b * 2 + u) * HW + (gy << 8) + gx]);
        }
        A18[p * 34 + kk] = v;
    }
    __syncthreads();

    f32x4 acc[4][8];
    #pragma unroll
    for (int i = 0; i < 4; ++i)
        #pragma unroll
        for (int mt = 0; mt < 8; ++mt) acc[i][mt] = (f32x4){0, 0, 0, 0};

    const int bbase = l15 * 4 + q;

    #define LOADB2(dst_, kc_) { \
        _Pragma("unroll") \
        for (int i = 0; i < 4; ++i) \
            dst_[i] = *(const short8*)(wr + ((size_t)(((kc_) * 16 + w * 4 + i) * 64 + bbase)) * 8); }
    #define COMP2(kc_, bf_) { \
        int rs_ = (kc_) >> 1, half_ = (kc_) & 1; \
        int r_ = rs_ / 3, s_ = rs_ % 3; \
        int rowb_ = r_ * 130 + s_ + l15; \
        _Pragma("unroll") \
        for (int mt = 0; mt < 8; ++mt) { \
            int row_ = rowb_ + mt * 16; \
            int col16_ = (half_ * 4 + q) ^ (row_ & 7); \
            short8 a_ = *(const short8*)(&ldsA[row_ * PADX2 + col16_ * 8]); \
            _Pragma("unroll") \
            for (int i = 0; i < 4; ++i) \
                acc[i][mt] = __builtin_amdgcn_mfma_f32_16x16x32_bf16(a_, bf_[i], acc[i][mt], 0, 0, 0); \
        } }

    short8 bA[4], bB[4];
    LOADB2(bA, 0);
    #pragma unroll 1
    for (int jj = 0; jj < 9; ++jj) {
        int kc0 = 2 * jj;
        LOADB2(bB, kc0 + 1);
        COMP2(kc0, bA);
        LOADB2(bA, kc0 + 2);     // jj==8 -> loads chunk 18 (flow B-frags)
        COMP2(kc0 + 1, bB);
    }
    // flow chunk (kc 18): A from A18
    #pragma unroll
    for (int mt = 0; mt < 8; ++mt) {
        short8 a_ = *(const short8*)(&A18[(mt * 16 + l15) * 34 + q * 8]);
        #pragma unroll
        for (int i = 0; i < 4; ++i)
            acc[i][mt] = __builtin_amdgcn_mfma_f32_16x16x32_bf16(a_, bA[i], acc[i][mt], 0, 0, 0);
    }
    #undef LOADB2
    #undef COMP2

    // epilogue: 2 passes; ch<144 -> OFF f32x4; ch>=144 -> sigmoid -> MB bf16
    #pragma unroll 1
    for (int pass = 0; pass < 2; ++pass) {
        __syncthreads();
        if ((w >> 1) == pass) {
            int ochl_base = (w & 1) * 64;
            #pragma unroll
            for (int i = 0; i < 4; ++i) {
                int ochl = ochl_base + i * 16 + l15;
                #pragma unroll
                for (int mt = 0; mt < 8; ++mt)
                    #pragma unroll
                    for (int rg = 0; rg < 4; ++rg)
                        ldsT[ochl * 132 + mt * 16 + q * 4 + rg] = acc[i][mt][rg];
            }
        }
        __syncthreads();
        for (int f = tid; f < 128 * 32; f += 256) {
            int chl = f >> 5, p16 = (f & 31) * 4;
            int ch = pass * 128 + chl;
            if (ch < 216) {
                f32x4 v = *(const f32x4*)(&ldsT[chl * 132 + p16]);
                float bv = bias[ch];
                if (ch < 144) {
                    v[0] += bv; v[1] += bv; v[2] += bv; v[3] += bv;
                    *(f32x4*)(&OFF[((size_t)b * 144 + ch) * HW + (yy << 8) + x0 + p16]) = v;
                } else {
                    union { bf16x4 bv4; sh4 s4; } u;
                    #pragma unroll
                    for (int j = 0; j < 4; ++j) {
                        float m = 1.f / (1.f + __expf(-(v[j] + bv)));
                        u.bv4[j] = (__bf16)m;
                    }
                    *(sh4*)(&MB[((size_t)b * 72 + (ch - 144)) * HW + (yy << 8) + x0 + p16]) = u.s4;
                }
            }
        }
    }
}

// ---------------------------------------------------------------------------
// dcn MFMA — pipelined; offsets from OFF (f32), mask from MB (bf16).
// Unchanged this round (at cross-run noise floor ~77-85us).
// ---------------------------------------------------------------------------
__global__ __launch_bounds__(256) void dcn_mfma_kernel(
    const float* __restrict__ OFF,    // (B,144,HW) f32
    const short* __restrict__ MB,     // (B,72,HW) bf16 sigmoid(mask)
    const float* __restrict__ flow,   // (B,2,HW)
    const short* __restrict__ N2,     // (B,8,HW,8) bf16 group-major
    const short* __restrict__ wrd,    // B-frag order, 49152
    const float* __restrict__ bias,   // 64
    float* __restrict__ out)          // (B,64,HW)
{
    __shared__ __align__(16) char ldsraw[26624];
    short* bufA = (short*)ldsraw;                 // [64 px][104]
    short* bufB = (short*)(ldsraw + 13312);       // [64 px][104]
    float* ldsT = (float*)ldsraw;                 // [64 och][68] epilogue alias

    const int tid = threadIdx.x;
    const int w = __builtin_amdgcn_readfirstlane(tid >> 6);
    const int l15 = tid & 15;
    const int q = (tid >> 4) & 3;
    const int qq = tid >> 6;
    const int px = tid & 63;

    const int blk = ((blockIdx.x & 7) << 8) | (blockIdx.x >> 3);  // XCD swizzle
    const int b = blk >> 10;
    const int grp = blk & 1023;
    const int pos0 = grp * 64;
    const int pos = pos0 + px;
    const int yy = pos >> 8, xx = pos & 255;

    const float* offb = OFF + (size_t)b * 144 * HW + pos;
    const short* mbp  = MB + (size_t)b * 72 * HW + pos;
    const float fx = flow[b * 2 * HW + pos];
    const float fy = flow[b * 2 * HW + HW + pos];
    const short* n2b = N2 + (size_t)b * HW * 64;

    // zero pad K-slots (k = 9..11) in BOTH buffers once
    {
        short8 z = {0, 0, 0, 0, 0, 0, 0, 0};
        #pragma unroll
        for (int it = 0; it < 3; ++it) {
            int k = qq + 4 * it;
            if (k >= 9) {
                *(short8*)(&bufA[px * 104 + k * 8]) = z;
                *(short8*)(&bufB[px * 104 + k * 8]) = z;
            }
        }
    }

    f32x4 acc[4] = {{0,0,0,0},{0,0,0,0},{0,0,0,0},{0,0,0,0}};

    // raw offset/mask loads for g=0
    float rdy[3], rdx[3];
    short rms[3];
    #pragma unroll
    for (int it = 0; it < 3; ++it) {
        int k = qq + 4 * it;
        rdy[it] = 0.f; rdx[it] = 0.f; rms[it] = 0;
        if (k < 9) {
            rdy[it] = offb[(size_t)(2 * k) * HW];
            rdx[it] = offb[(size_t)(2 * k + 1) * HW];
            rms[it] = mbp[(size_t)k * HW];
        }
    }

    // ---- prologue: fill group 0 into bufA ----
    {
        const short* nbg = n2b;                    // group 0 plane
        float w00[3], w01[3], w10[3], w11[3];
        short8 a00[3], a01[3], a10[3], a11[3];
        #pragma unroll
        for (int it = 0; it < 3; ++it) {
            int k = qq + 4 * it;
            if (k < 9) {
                float dy = rdy[it] + fy, dx = rdx[it] + fx;
                float m = bf2f(rms[it]);
                Taps tp = make_taps((float)(yy - 1 + k / 3) + dy,
                                    (float)(xx - 1 + k % 3) + dx);
                w00[it] = tp.w00 * m; w01[it] = tp.w01 * m;
                w10[it] = tp.w10 * m; w11[it] = tp.w11 * m;
                a00[it] = *(const short8*)(nbg + (size_t)tp.i00 * 8);
                a01[it] = *(const short8*)(nbg + (size_t)tp.i01 * 8);
                a10[it] = *(const short8*)(nbg + (size_t)tp.i10 * 8);
                a11[it] = *(const short8*)(nbg + (size_t)tp.i11 * 8);
            }
        }
        // prefetch raw g=1 (after the gathers: stays in flight through blend)
        #pragma unroll
        for (int it = 0; it < 3; ++it) {
            int k = qq + 4 * it;
            if (k < 9) {
                rdy[it] = offb[(size_t)(18 + 2 * k) * HW];
                rdx[it] = offb[(size_t)(18 + 2 * k + 1) * HW];
                rms[it] = mbp[(size_t)(9 + k) * HW];
            }
        }
        #pragma unroll
        for (int it = 0; it < 3; ++it) {
            int k = qq + 4 * it;
            if (k < 9) {
                union { bf16x8 bv; short8 s; } u;
                #pragma unroll
                for (int c = 0; c < 8; ++c) {
                    float s = w00[it] * bf2f(a00[it][c]) + w01[it] * bf2f(a01[it][c]) +
                              w10[it] * bf2f(a10[it][c]) + w11[it] * bf2f(a11[it][c]);
                    u.bv[c] = (__bf16)s;
                }
                *(short8*)(&bufA[px * 104 + k * 8]) = u.s;
            }
        }
    }
    __syncthreads();

    // ---- pipelined main loop: one barrier per group ----
    #pragma unroll 1
    for (int g = 0; g < 8; ++g) {
        short* cur = (g & 1) ? bufB : bufA;
        short* nxt = (g & 1) ? bufA : bufB;

        // issue gathers for group g+1 (12 loads in flight across the MFMAs)
        float w00[3], w01[3], w10[3], w11[3];
        short8 a00[3], a01[3], a10[3], a11[3];
        if (g < 7) {
            const short* nbg = n2b + (size_t)(g + 1) * HW * 8;
            #pragma unroll
            for (int it = 0; it < 3; ++it) {
                int k = qq + 4 * it;
                if (k < 9) {
                    float dy = rdy[it] + fy, dx = rdx[it] + fx;
                    float m = bf2f(rms[it]);
                    Taps tp = make_taps((float)(yy - 1 + k / 3) + dy,
                                        (float)(xx - 1 + k % 3) + dx);
                    w00[it] = tp.w00 * m; w01[it] = tp.w01 * m;
                    w10[it] = tp.w10 * m; w11[it] = tp.w11 * m;
                    a00[it] = *(const short8*)(nbg + (size_t)tp.i00 * 8);
                    a01[it] = *(const short8*)(nbg + (size_t)tp.i01 * 8);
                    a10[it] = *(const short8*)(nbg + (size_t)tp.i10 * 8);
                    a11[it] = *(const short8*)(nbg + (size_t)tp.i11 * 8);
                }
            }
            // prefetch raw for g+2 (after gathers: not drained by their wait)
            if (g < 6) {
                #pragma unroll
                for (int it = 0; it < 3; ++it) {
                    int k = qq + 4 * it;
                    if (k < 9) {
                        rdy[it] = offb[(size_t)((g + 2) * 18 + 2 * k) * HW];
                        rdx[it] = offb[(size_t)((g + 2) * 18 + 2 * k + 1) * HW];
                        rms[it] = mbp[(size_t)((g + 2) * 9 + k) * HW];
                    }
                }
            }
        }

        // MFMA group g from cur (hides the gather latency)
        #pragma unroll
        for (int kc = 0; kc < 3; ++kc) {
            short8 bfrag = *(const short8*)(wrd +
                ((size_t)(((g * 3 + kc) * 4 + w) * 64 + l15 * 4 + q)) * 8);
            #pragma unroll
            for (int mt = 0; mt < 4; ++mt) {
                short8 a = *(const short8*)(&cur[(mt * 16 + l15) * 104 + kc * 32 + q * 8]);
                acc[mt] = __builtin_amdgcn_mfma_f32_16x16x32_bf16(a, bfrag, acc[mt], 0, 0, 0);
            }
        }

        // blend g+1 -> nxt
        if (g < 7) {
            #pragma unroll
            for (int it = 0; it < 3; ++it) {
                int k = qq + 4 * it;
                if (k < 9) {
                    union { bf16x8 bv; short8 s; } u;
                    #pragma unroll
                    for (int c = 0; c < 8; ++c) {
                        float s = w00[it] * bf2f(a00[it][c]) + w01[it] * bf2f(a01[it][c]) +
                                  w10[it] * bf2f(a10[it][c]) + w11[it] * bf2f(a11[it][c]);
                        u.bv[c] = (__bf16)s;
                    }
                    *(short8*)(&nxt[px * 104 + k * 8]) = u.s;
                }
            }
        }
        __syncthreads();
    }

    // epilogue: LDS transpose (stride 68 -> 16B-aligned f32x4 rows) ->
    // vectorized NCHW stores (+bias)
    #pragma unroll
    for (int mt = 0; mt < 4; ++mt)
        *(f32x4*)(&ldsT[(w * 16 + l15) * 68 + mt * 16 + q * 4]) = acc[mt];
    __syncthreads();
    float* ob = out + (size_t)b * 64 * HW + pos0;
    #pragma unroll
    for (int f = tid; f < 1024; f += 256) {
        int och = f >> 4, p4 = (f & 15) * 4;
        f32x4 v = *(const f32x4*)(&ldsT[och * 68 + p4]);
        float bv = bias[och];
        v[0] += bv; v[1] += bv; v[2] += bv; v[3] += bv;
        *(f32x4*)(&ob[(size_t)och * HW + p4]) = v;
    }
}

// ---------------------------------------------------------------------------
extern "C" void kernel_launch(void* const* d_in, const int* in_sizes, int n_in,
                              void* d_out, int out_size, void* d_ws, size_t ws_size,
                              hipStream_t stream)
{
    const float* nbr  = (const float*)d_in[0];
    const float* ref  = (const float*)d_in[1];
    const float* flow = (const float*)d_in[2];
    const float* c1w  = (const float*)d_in[3];
    const float* c1b  = (const float*)d_in[4];
    const float* omw  = (const float*)d_in[5];
    const float* omb  = (const float*)d_in[6];
    const float* dw   = (const float*)d_in[7];
    const float* db   = (const float*)d_in[8];
    float* out = (float*)d_out;

    char* wsb = (char*)d_ws;
    short* X1    = (short*)(wsb);                  // 33,554,432 B
    short* X2    = (short*)(wsb + 33554432);       // 16,777,216 B
    short* N2    = (short*)(wsb + 50331648);       // 16,777,216 B
    float* OFF   = (float*)(wsb + 67108864);       // 75,497,472 B (B,144,HW f32)
    short* MB    = (short*)(wsb + 142606336);      // 18,874,368 B (B,72,HW bf16)
    short* wr1   = (short*)(wsb + 161480704);      // 147,456 B
    short* wr2   = (short*)(wsb + 161628160);      // 311,296 B
    short* wrd   = (short*)(wsb + 161939456);      // 98,304 B -> total 162,037,760 B

    repack_w1_kernel<<<288, 256, 0, stream>>>(c1w, wr1);
    repack_w2_kernel<<<608, 256, 0, stream>>>(omw, wr2);
    repack_dcn_kernel<<<192, 256, 0, stream>>>(dw, wrd);
    pack_nbr_kernel<<<2048, 256, 0, stream>>>(nbr, N2);
    pack_x1_kernel<<<2048, 256, 0, stream>>>(N2, ref, flow, X1);
    conv1_mfma_kernel<<<512, 256, 0, stream>>>(X1, c1b, wr1, X2);
    om_mfma_kernel<<<1024, 256, 0, stream>>>(X2, flow, wr2, omb, OFF, MB);
    dcn_mfma_kernel<<<2048, 256, 0, stream>>>(OFF, MB, flow, N2, wrd, db, out);
}

// Round 16
// 321.599 us; speedup vs baseline: 1.0119x; 1.0016x over previous
//
#include <hip/hip_runtime.h>
#include <math.h>

#define HW 65536
#define WD 256
#define HT 256

typedef short short8 __attribute__((ext_vector_type(8)));
typedef short sh4 __attribute__((ext_vector_type(4)));
typedef float f32x4 __attribute__((ext_vector_type(4)));
typedef __bf16 bf16x8 __attribute__((ext_vector_type(8)));
typedef __bf16 bf16x4 __attribute__((ext_vector_type(4)));

__device__ __forceinline__ short f2bf(float f) {
    union { float f; unsigned u; } v; v.f = f;
    unsigned r = (v.u + 0x7fffu + ((v.u >> 16) & 1u)) >> 16;
    return (short)r;
}

__device__ __forceinline__ float bf2f(short s) {
    union { unsigned u; float f; } v;
    v.u = ((unsigned)(unsigned short)s) << 16;
    return v.f;
}

__device__ __forceinline__ int iclamp(int v, int lo, int hi) {
    return v < lo ? lo : (v > hi ? hi : v);
}

struct Taps {
    int i00, i01, i10, i11;
    float w00, w01, w10, w11;
};

__device__ __forceinline__ Taps make_taps(float py, float px) {
    float fy0 = floorf(py), fx0 = floorf(px);
    float wy = py - fy0, wx = px - fx0;
    int y0 = (int)fy0, x0 = (int)fx0;
    int y1 = y0 + 1, x1 = x0 + 1;
    float vy0 = (y0 >= 0 && y0 <= HT - 1) ? 1.f : 0.f;
    float vy1 = (y1 >= 0 && y1 <= HT - 1) ? 1.f : 0.f;
    float vx0 = (x0 >= 0 && x0 <= WD - 1) ? 1.f : 0.f;
    float vx1 = (x1 >= 0 && x1 <= WD - 1) ? 1.f : 0.f;
    int yc0 = iclamp(y0, 0, HT - 1), yc1 = iclamp(y1, 0, HT - 1);
    int xc0 = iclamp(x0, 0, WD - 1), xc1 = iclamp(x1, 0, WD - 1);
    Taps t;
    t.i00 = yc0 * WD + xc0; t.i01 = yc0 * WD + xc1;
    t.i10 = yc1 * WD + xc0; t.i11 = yc1 * WD + xc1;
    t.w00 = (1.f - wy) * (1.f - wx) * vy0 * vx0;
    t.w01 = (1.f - wy) * wx * vy0 * vx1;
    t.w10 = wy * (1.f - wx) * vy1 * vx0;
    t.w11 = wy * wx * vy1 * vx1;
    return t;
}

// ---------------------------------------------------------------------------
// pack_nbr: nbr (B,64,HW) f32 -> N2 (B,8,HW,8) bf16 GROUP-MAJOR.
// Runs FIRST: N2 feeds pack_x1's warp gathers AND dcn's tap gathers.
// ---------------------------------------------------------------------------
__global__ __launch_bounds__(256) void pack_nbr_kernel(
    const float* __restrict__ nbr, short* __restrict__ N2)
{
    __shared__ short tile[64 * 66];
    int blk = blockIdx.x;              // b*1024 + grp
    int b = blk >> 10;
    int grp = blk & 1023;
    int px = threadIdx.x & 63;
    int qq = threadIdx.x >> 6;
    int pos = grp * 64 + px;

    const float* nb = nbr + (size_t)b * 64 * HW;
    #pragma unroll
    for (int j = 0; j < 16; ++j) {
        int c = qq * 16 + j;
        tile[px * 66 + c] = f2bf(nb[c * HW + pos]);
    }
    __syncthreads();

    short* xo = N2 + (size_t)b * HW * 64;
    #pragma unroll
    for (int f8 = threadIdx.x; f8 < 512; f8 += 256) {
        int g = f8 >> 6;        // group
        int p = f8 & 63;        // pixel (lanes contiguous -> coalesced)
        short8 v;
        #pragma unroll
        for (int j = 0; j < 8; ++j) v[j] = tile[p * 66 + g * 8 + j];
        *(short8*)(xo + ((size_t)g * HW + grp * 64 + p) * 8) = v;
    }
}

// ---------------------------------------------------------------------------
// pack_x1: warp from N2 (group-major bf16: 8 x 16B vector gathers/thread)
// + ref -> X1 (B,HW,128) NHWC bf16.
// ---------------------------------------------------------------------------
__global__ __launch_bounds__(256) void pack_x1_kernel(
    const short* __restrict__ N2, const float* __restrict__ ref,
    const float* __restrict__ flow, short* __restrict__ X1)
{
    __shared__ short tile[64 * 136];
    int blk = blockIdx.x;              // b*1024 + grp
    int b = blk >> 10;
    int grp = blk & 1023;
    int px = threadIdx.x & 63;
    int qq = threadIdx.x >> 6;
    int pos = grp * 64 + px;
    int yy = pos >> 8, xx = pos & 255;

    float fx = flow[b * 2 * HW + pos];
    float fy = flow[b * 2 * HW + HW + pos];
    Taps tp = make_taps((float)yy + fy, (float)xx + fx);

    const short* n2b = N2 + (size_t)b * HW * 64;
    const float* rf = ref + (size_t)b * 64 * HW;

    // warp channels: this thread covers groups qq*2, qq*2+1 (16 ch)
    #pragma unroll
    for (int gi = 0; gi < 2; ++gi) {
        int g = qq * 2 + gi;
        const short* nbg = n2b + (size_t)g * HW * 8;
        short8 a00 = *(const short8*)(nbg + (size_t)tp.i00 * 8);
        short8 a01 = *(const short8*)(nbg + (size_t)tp.i01 * 8);
        short8 a10 = *(const short8*)(nbg + (size_t)tp.i10 * 8);
        short8 a11 = *(const short8*)(nbg + (size_t)tp.i11 * 8);
        union { bf16x8 bv; short8 s; } u;
        #pragma unroll
        for (int c = 0; c < 8; ++c) {
            float s = tp.w00 * bf2f(a00[c]) + tp.w01 * bf2f(a01[c]) +
                      tp.w10 * bf2f(a10[c]) + tp.w11 * bf2f(a11[c]);
            u.bv[c] = (__bf16)s;
        }
        *(short8*)(&tile[px * 136 + g * 8]) = u.s;
    }
    // ref channels (coalesced channel-strided f32 reads)
    #pragma unroll
    for (int j = 0; j < 16; ++j) {
        int c = qq * 16 + j;
        tile[px * 136 + 64 + c] = f2bf(rf[c * HW + pos]);
    }
    __syncthreads();

    short* xo = X1 + ((size_t)b * HW + grp * 64) * 128;
    #pragma unroll
    for (int f8 = threadIdx.x; f8 < 1024; f8 += 256) {
        int p = (f8 * 8) >> 7;
        int c = (f8 * 8) & 127;
        short8 v;
        #pragma unroll
        for (int j = 0; j < 8; ++j) v[j] = tile[p * 136 + c + j];
        *(short8*)(xo + f8 * 8) = v;
    }
}

// ---------------------------------------------------------------------------
// Weight repacks to MFMA B-fragment order.
// ---------------------------------------------------------------------------
__global__ __launch_bounds__(256) void repack_w1_kernel(
    const float* __restrict__ w, short* __restrict__ wr)
{
    int t = blockIdx.x * 256 + threadIdx.x;  // 73728
    int j = t & 7, q = (t >> 3) & 3, l = (t >> 5) & 15;
    int nt = (t >> 9) & 3, kc = t >> 11;
    int k = kc * 32 + q * 8 + j;
    int rs = k >> 7, c = k & 127;
    int n = nt * 16 + l;
    wr[t] = f2bf(w[(n * 128 + c) * 9 + rs]);
}

// om weights -> B-frag order:
//   chunks 0..17: fea K (tap = k>>6, ch = k&63); chunk 18: flow (2*tap+u)
__global__ __launch_bounds__(256) void repack_w2_kernel(
    const float* __restrict__ w, short* __restrict__ wr)
{
    int t = blockIdx.x * 256 + threadIdx.x;  // 155648
    if (t >= 155648) return;
    int j = t & 7, q = (t >> 3) & 3, l = (t >> 5) & 15;
    int nt = (t >> 9) & 15, kc = t >> 13;
    int n = nt * 16 + l;
    float v = 0.f;
    if (kc < 18) {
        int k = kc * 32 + q * 8 + j;
        int rs = k >> 6, c = k & 63;
        if (n < 216) v = w[(n * 66 + c) * 9 + rs];
    } else {
        int k18 = q * 8 + j;
        if (k18 < 18 && n < 216) {
            int tap = k18 >> 1, u = k18 & 1;
            v = w[(n * 66 + 64 + u) * 9 + tap];
        }
    }
    wr[t] = f2bf(v);
}

// dcn weights -> B-frag order: flat = (((g*3+kc)*4+nt)*64 + l15*4+q)*8 + j
__global__ __launch_bounds__(256) void repack_dcn_kernel(
    const float* __restrict__ w, short* __restrict__ wr)
{
    int t = blockIdx.x * 256 + threadIdx.x;   // 49152
    int j = t & 7, q = (t >> 3) & 3, l = (t >> 5) & 15;
    int rem = t >> 9;           // (g*3+kc)*4 + nt
    int nt = rem & 3;
    int gkc = rem >> 2;         // g*3 + kc
    int kc = gkc % 3, g = gkc / 3;
    int Kidx = kc * 32 + q * 8 + j;
    int k = Kidx >> 3, c = Kidx & 7;
    int och = nt * 16 + l;
    float v = (k < 9) ? w[(och * 64 + g * 8 + c) * 9 + k] : 0.f;
    wr[t] = f2bf(v);
}

// ---------------------------------------------------------------------------
// conv1 MFMA: X1 (NHWC bf16, 128ch) -> X2 (NHWC bf16, 64ch fea only).
// 4-ROW BLOCKS (grid 512): halo staging redundancy 3.1x -> 1.55x (stage
// loads per output px halved). K processed in two 64-ch halves reusing one
// 49.5 KB LDS buffer (chunks kc%4 in {0,1} then {2,3}; both accumulate the
// same acc). Wave w owns output row w x all 64 och (acc[4][4]).
// ---------------------------------------------------------------------------
__global__ __launch_bounds__(256) void conv1_mfma_kernel(
    const short* __restrict__ X1, const float* __restrict__ bias,
    const short* __restrict__ wr, short* __restrict__ X2)
{
    __shared__ short lds[396 * 64];
    const int tid = threadIdx.x;
    const int w = __builtin_amdgcn_readfirstlane(tid >> 6);
    const int l15 = tid & 15;
    const int q = (tid >> 4) & 3;
    const int blk = ((blockIdx.x & 7) << 6) | (blockIdx.x >> 3);  // XCD swizzle (512 % 8 == 0)
    const int xseg = blk & 3;
    const int yq = (blk >> 2) & 63;
    const int b = blk >> 8;
    const int x0 = xseg * 64;
    const int y0r = yq * 4;

    const short* xin = X1 + (size_t)b * HW * 128;
    const int bbase = l15 * 4 + q;

    f32x4 acc[4][4];
    #pragma unroll
    for (int ot = 0; ot < 4; ++ot)
        #pragma unroll
        for (int mt = 0; mt < 4; ++mt) acc[ot][mt] = (f32x4){0, 0, 0, 0};

    #define LOADB1(dst_, t_) { \
        int kc_ = ((t_) >> 1) * 4 + h * 2 + ((t_) & 1); \
        _Pragma("unroll") \
        for (int ot = 0; ot < 4; ++ot) \
            dst_[ot] = *(const short8*)(wr + ((size_t)((kc_ * 4 + ot) * 64 + bbase)) * 8); }
    #define COMP1(t_, bf_) { \
        int rs_ = (t_) >> 1, cch_ = (t_) & 1; \
        int r_ = rs_ / 3, s_ = rs_ % 3; \
        int prow_ = (w + r_) * 66 + s_ + l15; \
        _Pragma("unroll") \
        for (int mt = 0; mt < 4; ++mt) { \
            int pr_ = prow_ + mt * 16; \
            int col16_ = (cch_ * 4 + q) ^ (pr_ & 7); \
            short8 a_ = *(const short8*)(&lds[pr_ * 64 + col16_ * 8]); \
            _Pragma("unroll") \
            for (int ot = 0; ot < 4; ++ot) \
                acc[ot][mt] = __builtin_amdgcn_mfma_f32_16x16x32_bf16(a_, bf_[ot], acc[ot][mt], 0, 0, 0); \
        } }

    #pragma unroll 1
    for (int h = 0; h < 2; ++h) {
        __syncthreads();       // protect lds from previous half's reads
        for (int i = tid; i < 396 * 8; i += 256) {
            int c8 = i & 7;
            int pix = i >> 3;
            int r = pix / 66, xx = pix - r * 66;
            int gy = y0r + r - 1, gx = x0 + xx - 1;
            short8 v = {0, 0, 0, 0, 0, 0, 0, 0};
            if (gy >= 0 && gy < HT && gx >= 0 && gx < WD)
                v = *(const short8*)(xin + ((size_t)((gy << 8) + gx)) * 128 + h * 64 + c8 * 8);
            *(short8*)(&lds[pix * 64 + ((c8 ^ (pix & 7)) * 8)]) = v;
        }
        __syncthreads();

        short8 bA[4], bB[4];
        LOADB1(bA, 0);
        #pragma unroll 1
        for (int jj = 0; jj < 9; ++jj) {
            int t0 = 2 * jj;
            LOADB1(bB, t0 + 1);
            COMP1(t0, bA);
            int t2 = t0 + 2; if (t2 > 17) t2 = 17;
            LOADB1(bA, t2);
            COMP1(t0 + 1, bB);
        }
    }
    #undef LOADB1
    #undef COMP1

    short* xo = X2 + (size_t)b * HW * 64;
    const int gyy = y0r + w;
    #pragma unroll
    for (int ot = 0; ot < 4; ++ot) {
        float bv = bias[ot * 16 + l15];
        #pragma unroll
        for (int mt = 0; mt < 4; ++mt) {
            #pragma unroll
            for (int rg = 0; rg < 4; ++rg) {
                int gpx = x0 + mt * 16 + q * 4 + rg;
                float v = fmaxf(acc[ot][mt][rg] + bv, 0.f);
                xo[((size_t)((gyy << 8) + gpx)) * 64 + ot * 16 + l15] = f2bf(v);
            }
        }
    }
}

// ---------------------------------------------------------------------------
// om MFMA: X2 (NHWC bf16, 64ch) + flow halo -> OFF (B,144,HW) f32 offsets
// + MB (B,72,HW) bf16 mask (sigmoid applied HERE, stored post-activation).
// M=128 px / block (grid 1024), acc[4][8].
// ---------------------------------------------------------------------------
#define PADX2 64
__global__ __launch_bounds__(256, 2) void om_mfma_kernel(
    const short* __restrict__ X2, const float* __restrict__ flow,
    const short* __restrict__ wr, const float* __restrict__ bias,
    float* __restrict__ OFF, short* __restrict__ MB)
{
    __shared__ __align__(16) char ldsraw[67584];
    short* ldsA = (short*)ldsraw;                  // [390][64] swizzled fea halo
    short* A18  = (short*)(ldsraw + 49920);        // [128][34] flow K-chunk
    float* ldsT = (float*)ldsraw;                  // [128][132] epilogue alias

    const int tid = threadIdx.x;
    const int w = __builtin_amdgcn_readfirstlane(tid >> 6);
    const int l15 = tid & 15;
    const int q = (tid >> 4) & 3;
    const int blk = ((blockIdx.x & 7) << 7) | (blockIdx.x >> 3);  // XCD swizzle (1024)
    const int xseg = blk & 1;
    const int yy = (blk >> 1) & 255;
    const int b = blk >> 9;
    const int x0 = xseg * 128;

    // stage fea halo: 3 rows x 130 px x 64 ch, XOR-swizzled 16B blocks
    const short* xin = X2 + (size_t)b * HW * 64;
    #pragma unroll
    for (int r = 0; r < 3; ++r) {
        int gy = yy + r - 1;
        for (int i = tid; i < 130 * 8; i += 256) {
            int xx = i >> 3, c8 = i & 7;
            int gx = x0 + xx - 1;
            short8 v = {0, 0, 0, 0, 0, 0, 0, 0};
            if (gy >= 0 && gy < HT && gx >= 0 && gx < WD)
                v = *(const short8*)(xin + ((size_t)((gy << 8) + gx)) * 64 + c8 * 8);
            int pix = r * 130 + xx;
            *(short8*)(&ldsA[pix * PADX2 + (c8 ^ (pix & 7)) * 8]) = v;
        }
    }
    // stage flow A-chunk [128 px][34]: cols 0..17 = flow halo, 18..31 zero
    for (int i = tid; i < 128 * 32; i += 256) {
        int p = i >> 5, kk = i & 31;
        short v = 0;
        if (kk < 18) {
            int tap = kk >> 1, u = kk & 1;
            int gy = yy + tap / 3 - 1, gx = x0 + p + tap % 3 - 1;
            if (gy >= 0 && gy < HT && gx >= 0 && gx < WD)
                v = f2bf(flow[(size_t)(b * 2 + u) * HW + (gy << 8) + gx]);
        }
        A18[p * 34 + kk] = v;
    }
    __syncthreads();

    f32x4 acc[4][8];
    #pragma unroll
    for (int i = 0; i < 4; ++i)
        #pragma unroll
        for (int mt = 0; mt < 8; ++mt) acc[i][mt] = (f32x4){0, 0, 0, 0};

    const int bbase = l15 * 4 + q;

    #define LOADB2(dst_, kc_) { \
        _Pragma("unroll") \
        for (int i = 0; i < 4; ++i) \
            dst_[i] = *(const short8*)(wr + ((size_t)(((kc_) * 16 + w * 4 + i) * 64 + bbase)) * 8); }
    #define COMP2(kc_, bf_) { \
        int rs_ = (kc_) >> 1, half_ = (kc_) & 1; \
        int r_ = rs_ / 3, s_ = rs_ % 3; \
        int rowb_ = r_ * 130 + s_ + l15; \
        _Pragma("unroll") \
        for (int mt = 0; mt < 8; ++mt) { \
            int row_ = rowb_ + mt * 16; \
            int col16_ = (half_ * 4 + q) ^ (row_ & 7); \
            short8 a_ = *(const short8*)(&ldsA[row_ * PADX2 + col16_ * 8]); \
            _Pragma("unroll") \
            for (int i = 0; i < 4; ++i) \
                acc[i][mt] = __builtin_amdgcn_mfma_f32_16x16x32_bf16(a_, bf_[i], acc[i][mt], 0, 0, 0); \
        } }

    short8 bA[4], bB[4];
    LOADB2(bA, 0);
    #pragma unroll 1
    for (int jj = 0; jj < 9; ++jj) {
        int kc0 = 2 * jj;
        LOADB2(bB, kc0 + 1);
        COMP2(kc0, bA);
        LOADB2(bA, kc0 + 2);     // jj==8 -> loads chunk 18 (flow B-frags)
        COMP2(kc0 + 1, bB);
    }
    // flow chunk (kc 18): A from A18
    #pragma unroll
    for (int mt = 0; mt < 8; ++mt) {
        short8 a_ = *(const short8*)(&A18[(mt * 16 + l15) * 34 + q * 8]);
        #pragma unroll
        for (int i = 0; i < 4; ++i)
            acc[i][mt] = __builtin_amdgcn_mfma_f32_16x16x32_bf16(a_, bA[i], acc[i][mt], 0, 0, 0);
    }
    #undef LOADB2
    #undef COMP2

    // epilogue: 2 passes; ch<144 -> OFF f32x4; ch>=144 -> sigmoid -> MB bf16
    #pragma unroll 1
    for (int pass = 0; pass < 2; ++pass) {
        __syncthreads();
        if ((w >> 1) == pass) {
            int ochl_base = (w & 1) * 64;
            #pragma unroll
            for (int i = 0; i < 4; ++i) {
                int ochl = ochl_base + i * 16 + l15;
                #pragma unroll
                for (int mt = 0; mt < 8; ++mt)
                    #pragma unroll
                    for (int rg = 0; rg < 4; ++rg)
                        ldsT[ochl * 132 + mt * 16 + q * 4 + rg] = acc[i][mt][rg];
            }
        }
        __syncthreads();
        for (int f = tid; f < 128 * 32; f += 256) {
            int chl = f >> 5, p16 = (f & 31) * 4;
            int ch = pass * 128 + chl;
            if (ch < 216) {
                f32x4 v = *(const f32x4*)(&ldsT[chl * 132 + p16]);
                float bv = bias[ch];
                if (ch < 144) {
                    v[0] += bv; v[1] += bv; v[2] += bv; v[3] += bv;
                    *(f32x4*)(&OFF[((size_t)b * 144 + ch) * HW + (yy << 8) + x0 + p16]) = v;
                } else {
                    union { bf16x4 bv4; sh4 s4; } u;
                    #pragma unroll
                    for (int j = 0; j < 4; ++j) {
                        float m = 1.f / (1.f + __expf(-(v[j] + bv)));
                        u.bv4[j] = (__bf16)m;
                    }
                    *(sh4*)(&MB[((size_t)b * 72 + (ch - 144)) * HW + (yy << 8) + x0 + p16]) = u.s4;
                }
            }
        }
    }
}

// ---------------------------------------------------------------------------
// dcn MFMA — pipelined; offsets from OFF (f32), mask from MB (bf16).
// At measured structural floor (77-86us across 6 schedule variants).
// ---------------------------------------------------------------------------
__global__ __launch_bounds__(256) void dcn_mfma_kernel(
    const float* __restrict__ OFF,    // (B,144,HW) f32
    const short* __restrict__ MB,     // (B,72,HW) bf16 sigmoid(mask)
    const float* __restrict__ flow,   // (B,2,HW)
    const short* __restrict__ N2,     // (B,8,HW,8) bf16 group-major
    const short* __restrict__ wrd,    // B-frag order, 49152
    const float* __restrict__ bias,   // 64
    float* __restrict__ out)          // (B,64,HW)
{
    __shared__ __align__(16) char ldsraw[26624];
    short* bufA = (short*)ldsraw;                 // [64 px][104]
    short* bufB = (short*)(ldsraw + 13312);       // [64 px][104]
    float* ldsT = (float*)ldsraw;                 // [64 och][68] epilogue alias

    const int tid = threadIdx.x;
    const int w = __builtin_amdgcn_readfirstlane(tid >> 6);
    const int l15 = tid & 15;
    const int q = (tid >> 4) & 3;
    const int qq = tid >> 6;
    const int px = tid & 63;

    const int blk = ((blockIdx.x & 7) << 8) | (blockIdx.x >> 3);  // XCD swizzle
    const int b = blk >> 10;
    const int grp = blk & 1023;
    const int pos0 = grp * 64;
    const int pos = pos0 + px;
    const int yy = pos >> 8, xx = pos & 255;

    const float* offb = OFF + (size_t)b * 144 * HW + pos;
    const short* mbp  = MB + (size_t)b * 72 * HW + pos;
    const float fx = flow[b * 2 * HW + pos];
    const float fy = flow[b * 2 * HW + HW + pos];
    const short* n2b = N2 + (size_t)b * HW * 64;

    // zero pad K-slots (k = 9..11) in BOTH buffers once
    {
        short8 z = {0, 0, 0, 0, 0, 0, 0, 0};
        #pragma unroll
        for (int it = 0; it < 3; ++it) {
            int k = qq + 4 * it;
            if (k >= 9) {
                *(short8*)(&bufA[px * 104 + k * 8]) = z;
                *(short8*)(&bufB[px * 104 + k * 8]) = z;
            }
        }
    }

    f32x4 acc[4] = {{0,0,0,0},{0,0,0,0},{0,0,0,0},{0,0,0,0}};

    // raw offset/mask loads for g=0
    float rdy[3], rdx[3];
    short rms[3];
    #pragma unroll
    for (int it = 0; it < 3; ++it) {
        int k = qq + 4 * it;
        rdy[it] = 0.f; rdx[it] = 0.f; rms[it] = 0;
        if (k < 9) {
            rdy[it] = offb[(size_t)(2 * k) * HW];
            rdx[it] = offb[(size_t)(2 * k + 1) * HW];
            rms[it] = mbp[(size_t)k * HW];
        }
    }

    // ---- prologue: fill group 0 into bufA ----
    {
        const short* nbg = n2b;                    // group 0 plane
        float w00[3], w01[3], w10[3], w11[3];
        short8 a00[3], a01[3], a10[3], a11[3];
        #pragma unroll
        for (int it = 0; it < 3; ++it) {
            int k = qq + 4 * it;
            if (k < 9) {
                float dy = rdy[it] + fy, dx = rdx[it] + fx;
                float m = bf2f(rms[it]);
                Taps tp = make_taps((float)(yy - 1 + k / 3) + dy,
                                    (float)(xx - 1 + k % 3) + dx);
                w00[it] = tp.w00 * m; w01[it] = tp.w01 * m;
                w10[it] = tp.w10 * m; w11[it] = tp.w11 * m;
                a00[it] = *(const short8*)(nbg + (size_t)tp.i00 * 8);
                a01[it] = *(const short8*)(nbg + (size_t)tp.i01 * 8);
                a10[it] = *(const short8*)(nbg + (size_t)tp.i10 * 8);
                a11[it] = *(const short8*)(nbg + (size_t)tp.i11 * 8);
            }
        }
        // prefetch raw g=1 (after the gathers: stays in flight through blend)
        #pragma unroll
        for (int it = 0; it < 3; ++it) {
            int k = qq + 4 * it;
            if (k < 9) {
                rdy[it] = offb[(size_t)(18 + 2 * k) * HW];
                rdx[it] = offb[(size_t)(18 + 2 * k + 1) * HW];
                rms[it] = mbp[(size_t)(9 + k) * HW];
            }
        }
        #pragma unroll
        for (int it = 0; it < 3; ++it) {
            int k = qq + 4 * it;
            if (k < 9) {
                union { bf16x8 bv; short8 s; } u;
                #pragma unroll
                for (int c = 0; c < 8; ++c) {
                    float s = w00[it] * bf2f(a00[it][c]) + w01[it] * bf2f(a01[it][c]) +
                              w10[it] * bf2f(a10[it][c]) + w11[it] * bf2f(a11[it][c]);
                    u.bv[c] = (__bf16)s;
                }
                *(short8*)(&bufA[px * 104 + k * 8]) = u.s;
            }
        }
    }
    __syncthreads();

    // ---- pipelined main loop: one barrier per group ----
    #pragma unroll 1
    for (int g = 0; g < 8; ++g) {
        short* cur = (g & 1) ? bufB : bufA;
        short* nxt = (g & 1) ? bufA : bufB;

        // issue gathers for group g+1 (12 loads in flight across the MFMAs)
        float w00[3], w01[3], w10[3], w11[3];
        short8 a00[3], a01[3], a10[3], a11[3];
        if (g < 7) {
            const short* nbg = n2b + (size_t)(g + 1) * HW * 8;
            #pragma unroll
            for (int it = 0; it < 3; ++it) {
                int k = qq + 4 * it;
                if (k < 9) {
                    float dy = rdy[it] + fy, dx = rdx[it] + fx;
                    float m = bf2f(rms[it]);
                    Taps tp = make_taps((float)(yy - 1 + k / 3) + dy,
                                        (float)(xx - 1 + k % 3) + dx);
                    w00[it] = tp.w00 * m; w01[it] = tp.w01 * m;
                    w10[it] = tp.w10 * m; w11[it] = tp.w11 * m;
                    a00[it] = *(const short8*)(nbg + (size_t)tp.i00 * 8);
                    a01[it] = *(const short8*)(nbg + (size_t)tp.i01 * 8);
                    a10[it] = *(const short8*)(nbg + (size_t)tp.i10 * 8);
                    a11[it] = *(const short8*)(nbg + (size_t)tp.i11 * 8);
                }
            }
            // prefetch raw for g+2 (after gathers: not drained by their wait)
            if (g < 6) {
                #pragma unroll
                for (int it = 0; it < 3; ++it) {
                    int k = qq + 4 * it;
                    if (k < 9) {
                        rdy[it] = offb[(size_t)((g + 2) * 18 + 2 * k) * HW];
                        rdx[it] = offb[(size_t)((g + 2) * 18 + 2 * k + 1) * HW];
                        rms[it] = mbp[(size_t)((g + 2) * 9 + k) * HW];
                    }
                }
            }
        }

        // MFMA group g from cur (hides the gather latency)
        #pragma unroll
        for (int kc = 0; kc < 3; ++kc) {
            short8 bfrag = *(const short8*)(wrd +
                ((size_t)(((g * 3 + kc) * 4 + w) * 64 + l15 * 4 + q)) * 8);
            #pragma unroll
            for (int mt = 0; mt < 4; ++mt) {
                short8 a = *(const short8*)(&cur[(mt * 16 + l15) * 104 + kc * 32 + q * 8]);
                acc[mt] = __builtin_amdgcn_mfma_f32_16x16x32_bf16(a, bfrag, acc[mt], 0, 0, 0);
            }
        }

        // blend g+1 -> nxt
        if (g < 7) {
            #pragma unroll
            for (int it = 0; it < 3; ++it) {
                int k = qq + 4 * it;
                if (k < 9) {
                    union { bf16x8 bv; short8 s; } u;
                    #pragma unroll
                    for (int c = 0; c < 8; ++c) {
                        float s = w00[it] * bf2f(a00[it][c]) + w01[it] * bf2f(a01[it][c]) +
                                  w10[it] * bf2f(a10[it][c]) + w11[it] * bf2f(a11[it][c]);
                        u.bv[c] = (__bf16)s;
                    }
                    *(short8*)(&nxt[px * 104 + k * 8]) = u.s;
                }
            }
        }
        __syncthreads();
    }

    // epilogue: LDS transpose (stride 68 -> 16B-aligned f32x4 rows) ->
    // vectorized NCHW stores (+bias)
    #pragma unroll
    for (int mt = 0; mt < 4; ++mt)
        *(f32x4*)(&ldsT[(w * 16 + l15) * 68 + mt * 16 + q * 4]) = acc[mt];
    __syncthreads();
    float* ob = out + (size_t)b * 64 * HW + pos0;
    #pragma unroll
    for (int f = tid; f < 1024; f += 256) {
        int och = f >> 4, p4 = (f & 15) * 4;
        f32x4 v = *(const f32x4*)(&ldsT[och * 68 + p4]);
        float bv = bias[och];
        v[0] += bv; v[1] += bv; v[2] += bv; v[3] += bv;
        *(f32x4*)(&ob[(size_t)och * HW + p4]) = v;
    }
}

// ---------------------------------------------------------------------------
extern "C" void kernel_launch(void* const* d_in, const int* in_sizes, int n_in,
                              void* d_out, int out_size, void* d_ws, size_t ws_size,
                              hipStream_t stream)
{
    const float* nbr  = (const float*)d_in[0];
    const float* ref  = (const float*)d_in[1];
    const float* flow = (const float*)d_in[2];
    const float* c1w  = (const float*)d_in[3];
    const float* c1b  = (const float*)d_in[4];
    const float* omw  = (const float*)d_in[5];
    const float* omb  = (const float*)d_in[6];
    const float* dw   = (const float*)d_in[7];
    const float* db   = (const float*)d_in[8];
    float* out = (float*)d_out;

    char* wsb = (char*)d_ws;
    short* X1    = (short*)(wsb);                  // 33,554,432 B
    short* X2    = (short*)(wsb + 33554432);       // 16,777,216 B
    short* N2    = (short*)(wsb + 50331648);       // 16,777,216 B
    float* OFF   = (float*)(wsb + 67108864);       // 75,497,472 B (B,144,HW f32)
    short* MB    = (short*)(wsb + 142606336);      // 18,874,368 B (B,72,HW bf16)
    short* wr1   = (short*)(wsb + 161480704);      // 147,456 B
    short* wr2   = (short*)(wsb + 161628160);      // 311,296 B
    short* wrd   = (short*)(wsb + 161939456);      // 98,304 B -> total 162,037,760 B

    repack_w1_kernel<<<288, 256, 0, stream>>>(c1w, wr1);
    repack_w2_kernel<<<608, 256, 0, stream>>>(omw, wr2);
    repack_dcn_kernel<<<192, 256, 0, stream>>>(dw, wrd);
    pack_nbr_kernel<<<2048, 256, 0, stream>>>(nbr, N2);
    pack_x1_kernel<<<2048, 256, 0, stream>>>(N2, ref, flow, X1);
    conv1_mfma_kernel<<<512, 256, 0, stream>>>(X1, c1b, wr1, X2);
    om_mfma_kernel<<<1024, 256, 0, stream>>>(X2, flow, wr2, omb, OFF, MB);
    dcn_mfma_kernel<<<2048, 256, 0, stream>>>(OFF, MB, flow, N2, wrd, db, out);
}